// Round 2
// baseline (549.058 us; speedup 1.0000x reference)
//
#include <hip/hip_runtime.h>
#include <cstdint>
#include <cstddef>

// Problem constants: B=64, T=2048, M=512, P=512

typedef float  floatx4 __attribute__((ext_vector_type(4)));
typedef short  shortx8 __attribute__((ext_vector_type(8)));

__device__ __forceinline__ short f2bf_rne(float f) {
  unsigned u = __float_as_uint(f);
  unsigned r = u + 0x7FFFu + ((u >> 16) & 1u);
  return (short)(r >> 16);
}
__device__ __forceinline__ unsigned pack2_rne(float lo, float hi) {
  return (unsigned)(unsigned short)f2bf_rne(lo) |
         ((unsigned)(unsigned short)f2bf_rne(hi) << 16);
}
// pack two fp32 -> two bf16 (truncation) in one v_perm_b32 (fallback path)
__device__ __forceinline__ unsigned pack_bf_trunc(float lo, float hi) {
  return __builtin_amdgcn_perm(__float_as_uint(hi), __float_as_uint(lo), 0x07060302u);
}

#define GLOAD_LDS16(gptr, lptr)                                                 \
  __builtin_amdgcn_global_load_lds(                                             \
      (const __attribute__((address_space(1))) void*)(gptr),                    \
      (__attribute__((address_space(3))) void*)(lptr), 16, 0, 0)

// ---------------------------------------------------------------------------
// Kernel 1: prep.
//  blocks [0,128):    S[b][n] = ds@W_d + b_wd + b_ud (fp32), 4 indep fma chains
//  blocks [128,192):  U_T[n][k] = bf16(U_d[k][n]) via LDS 64x64 tile transpose
//  blocks [192,320):  zero d_out (logit accumulator)
//  blocks [320, 320+32768): Abf = bf16_rne(encoder_h)  (268MB -> 134MB, BW-bound)
// Fallback mode: launched with grid=320 (no Abf blocks).
// ---------------------------------------------------------------------------
extern "C" __global__ __launch_bounds__(256) void prep_kernel(
    const float* __restrict__ hidden, const float* __restrict__ cell,
    const float* __restrict__ W_d, const float* __restrict__ b_wd,
    const float* __restrict__ U_d, const float* __restrict__ b_ud,
    const float* __restrict__ enc,
    float* __restrict__ S, short* __restrict__ UT, short* __restrict__ Abf,
    float* __restrict__ lzero)
{
  __shared__ short Ls[64 * 65];
  const int bx = blockIdx.x, tid = threadIdx.x;
  if (bx >= 320) {
    size_t i0 = (size_t)(bx - 320) * 2048 + (size_t)tid * 8;
    floatx4 a = *(const floatx4*)(enc + i0);
    floatx4 b = *(const floatx4*)(enc + i0 + 4);
    union { shortx8 s; unsigned u[4]; } o;
    o.u[0] = pack2_rne(a.x, a.y);
    o.u[1] = pack2_rne(a.z, a.w);
    o.u[2] = pack2_rne(b.x, b.y);
    o.u[3] = pack2_rne(b.z, b.w);
    *(shortx8*)(Abf + i0) = o.s;
  } else if (bx < 128) {
    int idx = bx * 256 + tid;          // 0..32767
    int b = idx >> 9, n = idx & 511;
    const float* h = hidden + b * 512;
    const float* c = cell   + b * 512;
    float a0 = b_wd[n] + b_ud[n], a1 = 0.f, a2 = 0.f, a3 = 0.f;
    for (int k = 0; k < 512; k += 4) {
      a0 = fmaf(h[k + 0], W_d[(k + 0) * 512 + n], a0);
      a1 = fmaf(h[k + 1], W_d[(k + 1) * 512 + n], a1);
      a2 = fmaf(h[k + 2], W_d[(k + 2) * 512 + n], a2);
      a3 = fmaf(h[k + 3], W_d[(k + 3) * 512 + n], a3);
    }
    for (int k = 0; k < 512; k += 4) {
      a0 = fmaf(c[k + 0], W_d[(512 + k + 0) * 512 + n], a0);
      a1 = fmaf(c[k + 1], W_d[(512 + k + 1) * 512 + n], a1);
      a2 = fmaf(c[k + 2], W_d[(512 + k + 2) * 512 + n], a2);
      a3 = fmaf(c[k + 3], W_d[(512 + k + 3) * 512 + n], a3);
    }
    S[idx] = (a0 + a1) + (a2 + a3);
  } else if (bx < 192) {
    // 64x64 tile transpose, coalesced reads and writes
    int bt = bx - 128;
    int k0 = (bt >> 3) * 64, n0 = (bt & 7) * 64;
#pragma unroll
    for (int it = 0; it < 16; ++it) {
      int e = it * 256 + tid;
      int r = e >> 6, c = e & 63;
      Ls[r * 65 + c] = f2bf_rne(U_d[(size_t)(k0 + r) * 512 + n0 + c]);
    }
    __syncthreads();
#pragma unroll
    for (int it = 0; it < 16; ++it) {
      int e = it * 256 + tid;
      int rn = e >> 6, ck = e & 63;
      UT[(size_t)(n0 + rn) * 512 + k0 + ck] = Ls[ck * 65 + rn];
    }
  } else {
    int idx = ((bx - 192) * 256 + tid) * 4;
    *(floatx4*)(lzero + idx) = (floatx4){0.f, 0.f, 0.f, 0.f};
  }
}

// ---------------------------------------------------------------------------
// Kernel 2 (fast path): bf16 GEMM + tanh + dot(v) -> atomicAdd partial logits
// A = Abf (131072 x 512) bf16, B = UT (512n x 512k) bf16.
// 128x128 tile, 4 waves 2x2, mfma 16x16x32 bf16, BK=64 (8 K-iters).
// Both LDS tiles XOR-swizzled at 16B granule: phys = logical ^ (row&7);
// applied on the GLOBAL source k-offset so global_load_lds stays contiguous.
// Frag reads are provably balanced: 8 lanes per 4-bank group = minimum phases.
// ---------------------------------------------------------------------------
extern "C" __global__ __launch_bounds__(256, 4) void attn_gemm_bf(
    const short* __restrict__ A, const short* __restrict__ UT,
    const float* __restrict__ S, const float* __restrict__ vd,
    float* __restrict__ lout)
{
  __shared__ short As[128 * 64];   // 16 KB
  __shared__ short Bs[128 * 64];   // 16 KB

  const int tid = threadIdx.x;
  const int bx  = blockIdx.x;
  const int xcd = bx & 7;
  const int k7  = bx >> 3;
  const int rb  = xcd * 128 + (k7 >> 2);
  const int cb  = k7 & 3;
  const int row0 = rb * 128;
  const int col0 = cb * 128;
  const int wave = tid >> 6;
  const int lane = tid & 63;
  const int wr = wave >> 1, wc = wave & 1;
  const int q = lane >> 4, l15 = lane & 15;

  // staging source offsets (shorts); chunk c = j*64+lane, row m = wave*32+(c>>3),
  // phys chunk p = c&7 holds logical chunk l = p ^ (m&7)
  int aoffg[4], boffg[4];
#pragma unroll
  for (int j = 0; j < 4; ++j) {
    int c = j * 64 + lane;
    int r = c >> 3, p = c & 7;
    int m = wave * 32 + r;
    int l = p ^ (m & 7);
    aoffg[j] = (row0 + m) * 512 + l * 8;
    boffg[j] = (col0 + m) * 512 + l * 8;
  }

  // frag read base offsets (shorts); logical chunk ks*4+q -> phys ^ (l15&7)
  const int arow = (wr * 64 + l15) * 64;
  const int brow = (wc * 64 + l15) * 64;
  const int s7 = l15 & 7;
  const int abase0 = arow + ((q) ^ s7) * 8;
  const int abase1 = arow + ((4 + q) ^ s7) * 8;
  const int bbase0 = brow + ((q) ^ s7) * 8;
  const int bbase1 = brow + ((4 + q) ^ s7) * 8;

  floatx4 acc[4][4];
#pragma unroll
  for (int i = 0; i < 4; ++i)
#pragma unroll
    for (int j = 0; j < 4; ++j)
      acc[i][j] = (floatx4){0.f, 0.f, 0.f, 0.f};

  for (int kk = 0; kk < 512; kk += 64) {
    __syncthreads();
#pragma unroll
    for (int j = 0; j < 4; ++j)
      GLOAD_LDS16(A + aoffg[j] + kk, &As[wave * 2048 + j * 512]);
#pragma unroll
    for (int j = 0; j < 4; ++j)
      GLOAD_LDS16(UT + boffg[j] + kk, &Bs[wave * 2048 + j * 512]);
    __syncthreads();   // implies vmcnt(0): tiles ready

    shortx8 af[4], bf[4];
#pragma unroll
    for (int t = 0; t < 4; ++t) {
      af[t] = *(const shortx8*)(As + abase0 + t * 1024);
      bf[t] = *(const shortx8*)(Bs + bbase0 + t * 1024);
    }
#pragma unroll
    for (int tr = 0; tr < 4; ++tr)
#pragma unroll
      for (int tc = 0; tc < 4; ++tc)
        acc[tr][tc] = __builtin_amdgcn_mfma_f32_16x16x32_bf16(
            af[tr], bf[tc], acc[tr][tc], 0, 0, 0);
#pragma unroll
    for (int t = 0; t < 4; ++t) {
      af[t] = *(const shortx8*)(As + abase1 + t * 1024);
      bf[t] = *(const shortx8*)(Bs + bbase1 + t * 1024);
    }
#pragma unroll
    for (int tr = 0; tr < 4; ++tr)
#pragma unroll
      for (int tc = 0; tc < 4; ++tc)
        acc[tr][tc] = __builtin_amdgcn_mfma_f32_16x16x32_bf16(
            af[tr], bf[tc], acc[tr][tc], 0, 0, 0);
  }

  // epilogue: e = tanh(acc + S[b][n]); partial = sum_n e*v[n]; atomicAdd rows
  const float* Srow = S + (row0 >> 11) * 512;
#pragma unroll
  for (int tr = 0; tr < 4; ++tr) {
#pragma unroll
    for (int r = 0; r < 4; ++r) {
      float ssum = 0.f;
#pragma unroll
      for (int tc = 0; tc < 4; ++tc) {
        int n = col0 + wc * 64 + tc * 16 + l15;
        float x = acc[tr][tc][r] + Srow[n];
        x = fminf(15.f, fmaxf(-15.f, x));
        float e2 = __expf(2.f * x);
        ssum += ((e2 - 1.f) / (e2 + 1.f)) * vd[n];
      }
      ssum += __shfl_xor(ssum, 1);
      ssum += __shfl_xor(ssum, 2);
      ssum += __shfl_xor(ssum, 4);
      ssum += __shfl_xor(ssum, 8);
      if (l15 == 0) {
        int row = row0 + wr * 64 + tr * 16 + q * 4 + r;
        atomicAdd(lout + row, ssum);
      }
    }
  }
}

// ---------------------------------------------------------------------------
// Kernel 2 (fallback, R1-verified): fp32-staged GEMM with in-loop convert.
// Used only if ws_size can't hold the bf16 A buffer.
// ---------------------------------------------------------------------------
extern "C" __global__ __launch_bounds__(256) void attn_gemm_f32(
    const float* __restrict__ A, const short* __restrict__ UT,
    const float* __restrict__ S, const float* __restrict__ vd,
    float* __restrict__ lout)
{
  __shared__ float Asw[128 * 32];
  __shared__ short Bs[128 * 32];

  const int tid = threadIdx.x;
  const int bx  = blockIdx.x;
  const int xcd = bx & 7;
  const int k7  = bx >> 3;
  const int rb  = xcd * 128 + (k7 >> 2);
  const int cb  = k7 & 3;
  const int row0 = rb * 128;
  const int col0 = cb * 128;
  const int wave = tid >> 6;
  const int lane = tid & 63;
  const int wr = wave >> 1, wc = wave & 1;
  const int q = lane >> 4, l15 = lane & 15;

  const float* asrc[4];
#pragma unroll
  for (int j = 0; j < 4; ++j) {
    int c = wave * 4 + j;
    int m = c * 8 + (lane >> 3);
    int pl = (lane & 7) ^ (m & 7);
    asrc[j] = A + (size_t)(row0 + m) * 512 + pl * 4;
  }
  const short* bsrc[2];
#pragma unroll
  for (int j = 0; j < 2; ++j) {
    int c = wave * 2 + j;
    int n = c * 16 + (lane >> 2);
    int ks = (lane & 3) * 8;
    bsrc[j] = UT + (size_t)(col0 + n) * 512 + ks;
  }

  int aoff0[4], aoff1[4], boff[4];
#pragma unroll
  for (int t = 0; t < 4; ++t) {
    int m = wr * 64 + t * 16 + l15;
    int s = m & 7;
    aoff0[t] = m * 32 + (((2 * q) ^ s) << 2);
    aoff1[t] = m * 32 + ((((2 * q) | 1) ^ s) << 2);
    int n = wc * 64 + t * 16 + l15;
    boff[t] = n * 32 + q * 8;
  }

  floatx4 acc[4][4];
#pragma unroll
  for (int i = 0; i < 4; ++i)
#pragma unroll
    for (int j = 0; j < 4; ++j)
      acc[i][j] = (floatx4){0.f, 0.f, 0.f, 0.f};

  for (int kk = 0; kk < 512; kk += 32) {
    __syncthreads();
#pragma unroll
    for (int j = 0; j < 4; ++j)
      GLOAD_LDS16(asrc[j] + kk, &Asw[(wave * 4 + j) * 256]);
#pragma unroll
    for (int j = 0; j < 2; ++j)
      GLOAD_LDS16(bsrc[j] + kk, &Bs[(wave * 2 + j) * 512]);
    __syncthreads();

    shortx8 af[4], bf[4];
#pragma unroll
    for (int t = 0; t < 4; ++t) {
      floatx4 a0 = *(const floatx4*)(Asw + aoff0[t]);
      floatx4 a1 = *(const floatx4*)(Asw + aoff1[t]);
      union { shortx8 v; unsigned u[4]; } fu;
      fu.u[0] = pack_bf_trunc(a0.x, a0.y);
      fu.u[1] = pack_bf_trunc(a0.z, a0.w);
      fu.u[2] = pack_bf_trunc(a1.x, a1.y);
      fu.u[3] = pack_bf_trunc(a1.z, a1.w);
      af[t] = fu.v;
      bf[t] = *(const shortx8*)(Bs + boff[t]);
    }
#pragma unroll
    for (int tr = 0; tr < 4; ++tr)
#pragma unroll
      for (int tc = 0; tc < 4; ++tc)
        acc[tr][tc] = __builtin_amdgcn_mfma_f32_16x16x32_bf16(
            af[tr], bf[tc], acc[tr][tc], 0, 0, 0);
  }

  const float* Srow = S + (row0 >> 11) * 512;
#pragma unroll
  for (int tr = 0; tr < 4; ++tr) {
#pragma unroll
    for (int r = 0; r < 4; ++r) {
      float ssum = 0.f;
#pragma unroll
      for (int tc = 0; tc < 4; ++tc) {
        int n = col0 + wc * 64 + tc * 16 + l15;
        float x = acc[tr][tc][r] + Srow[n];
        x = fminf(15.f, fmaxf(-15.f, x));
        float e2 = __expf(2.f * x);
        ssum += ((e2 - 1.f) / (e2 + 1.f)) * vd[n];
      }
      ssum += __shfl_xor(ssum, 1);
      ssum += __shfl_xor(ssum, 2);
      ssum += __shfl_xor(ssum, 4);
      ssum += __shfl_xor(ssum, 8);
      if (l15 == 0) {
        int row = row0 + wr * 64 + tr * 16 + q * 4 + r;
        atomicAdd(lout + row, ssum);
      }
    }
  }
}

// ---------------------------------------------------------------------------
// Kernel 3: softmax over T=2048, in place on d_out. One block per batch.
// ---------------------------------------------------------------------------
extern "C" __global__ __launch_bounds__(256) void softmax_t(float* __restrict__ l)
{
  int b = blockIdx.x, tid = threadIdx.x;
  int wave = tid >> 6, lane = tid & 63;
  float* row = l + (size_t)b * 2048;
  float v[8];
  float mx = -3.4e38f;
#pragma unroll
  for (int i = 0; i < 8; ++i) { v[i] = row[tid + i * 256]; mx = fmaxf(mx, v[i]); }
#pragma unroll
  for (int m = 1; m < 64; m <<= 1) mx = fmaxf(mx, __shfl_xor(mx, m));
  __shared__ float red[8];
  if (lane == 0) red[wave] = mx;
  __syncthreads();
  mx = fmaxf(fmaxf(red[0], red[1]), fmaxf(red[2], red[3]));
  float s = 0.f;
#pragma unroll
  for (int i = 0; i < 8; ++i) { v[i] = __expf(v[i] - mx); s += v[i]; }
#pragma unroll
  for (int m = 1; m < 64; m <<= 1) s += __shfl_xor(s, m);
  if (lane == 0) red[4 + wave] = s;
  __syncthreads();
  s = red[4] + red[5] + red[6] + red[7];
  float inv = 1.f / s;
#pragma unroll
  for (int i = 0; i < 8; ++i) row[tid + i * 256] = v[i] * inv;
}

// ---------------------------------------------------------------------------
extern "C" void kernel_launch(void* const* d_in, const int* in_sizes, int n_in,
                              void* d_out, int out_size, void* d_ws, size_t ws_size,
                              hipStream_t stream) {
  const float* hidden = (const float*)d_in[0];
  const float* cell   = (const float*)d_in[1];
  const float* enc    = (const float*)d_in[2];
  const float* W_d    = (const float*)d_in[3];
  const float* b_wd   = (const float*)d_in[4];
  const float* U_d    = (const float*)d_in[5];
  const float* b_ud   = (const float*)d_in[6];
  const float* v_d    = (const float*)d_in[7];
  // d_in[8] = b_vd: constant shift over T -> softmax-invariant, unused.
  float* out = (float*)d_out;
  float* S   = (float*)d_ws;                                  // 128 KB
  short* UT  = (short*)((char*)d_ws + 131072);                // 512 KB
  short* Abf = (short*)((char*)d_ws + 131072 + 524288);       // 128 MB bf16 A

  const size_t need = 131072ull + 524288ull + 134217728ull;
  if (ws_size >= need) {
    hipLaunchKernelGGL(prep_kernel, dim3(320 + 32768), dim3(256), 0, stream,
                       hidden, cell, W_d, b_wd, U_d, b_ud, enc, S, UT, Abf, out);
    hipLaunchKernelGGL(attn_gemm_bf, dim3(4096), dim3(256), 0, stream,
                       Abf, UT, S, v_d, out);
  } else {
    hipLaunchKernelGGL(prep_kernel, dim3(320), dim3(256), 0, stream,
                       hidden, cell, W_d, b_wd, U_d, b_ud, enc, S, UT, Abf, out);
    hipLaunchKernelGGL(attn_gemm_f32, dim3(4096), dim3(256), 0, stream,
                       enc, UT, S, v_d, out);
  }
  hipLaunchKernelGGL(softmax_t, dim3(64), dim3(256), 0, stream, out);
}